// Round 1
// baseline (1240.334 us; speedup 1.0000x reference)
//
#include <hip/hip_runtime.h>
#include <math.h>

#define FDIM 128
#define RDIM 20
#define BN   8000
#define NPAIR 512000
#define PB   64
#define NCHUNK (NPAIR/PB)

// ShiftedSoftplus: softplus(x) - log(2), stable form
__device__ __forceinline__ float sspf(float x) {
    return fmaxf(x, 0.0f) + log1pf(expf(-fabsf(x))) - 0.69314718055994531f;
}

// C[p, :] = act(A[p, :] @ W + bias), 16 rows per block, 256 threads.
template<bool SSP>
__global__ __launch_bounds__(256) void rowgemm_kernel(
    const float* __restrict__ A, const float* __restrict__ W,
    const float* __restrict__ bias, float* __restrict__ C)
{
    __shared__ float rowlds[16 * 128];
    const int tid = threadIdx.x;
    const int blk = blockIdx.x;
    for (int s = tid; s < 16 * 128; s += 256)
        rowlds[s] = A[blk * 16 * 128 + s];
    __syncthreads();

    const int lane = tid & 63;
    const int wave = tid >> 6;
    const float b0 = bias[lane];
    const float b1 = bias[64 + lane];
    float acc[4][2];
    #pragma unroll
    for (int rr = 0; rr < 4; ++rr) { acc[rr][0] = b0; acc[rr][1] = b1; }

    #pragma unroll 4
    for (int m = 0; m < 128; ++m) {
        const float w0 = W[m * 128 + lane];
        const float w1 = W[m * 128 + 64 + lane];
        #pragma unroll
        for (int rr = 0; rr < 4; ++rr) {
            const float av = rowlds[(wave * 4 + rr) * 128 + m];
            acc[rr][0] = fmaf(av, w0, acc[rr][0]);
            acc[rr][1] = fmaf(av, w1, acc[rr][1]);
        }
    }

    #pragma unroll
    for (int rr = 0; rr < 4; ++rr) {
        const int p = blk * 16 + wave * 4 + rr;
        float v0 = acc[rr][0], v1 = acc[rr][1];
        if (SSP) { v0 = sspf(v0); v1 = sspf(v1); }
        C[p * 128 + lane]      = v0;
        C[p * 128 + 64 + lane] = v1;
    }
}

// Fused filter-network + gather + scatter-add over pairs.
// gridDim.y = 2: each y-half owns output columns [y*64, y*64+64).
__global__ __launch_bounds__(256) void pairs_kernel(
    const float* __restrict__ f_ij, const int* __restrict__ idx_i,
    const int* __restrict__ idx_j, const float* __restrict__ rcut,
    const float* __restrict__ Wf1, const float* __restrict__ bf1,
    const float* __restrict__ Wf2, const float* __restrict__ bf2,
    const float* __restrict__ h, float* __restrict__ agg)
{
    __shared__ float w2[128][64];       // Wf2[:, cbase:cbase+64]   32 KB
    __shared__ float wf1[RDIM * 128];   // Wf1                      10 KB
    __shared__ float act[32][PB];       // k-tile of ssp(layer1)     8 KB
    __shared__ float fst[PB][21];       // f_ij rows (pad 20->21)  5.25 KB
    __shared__ int   iis[PB];
    __shared__ int   jjs[PB];
    __shared__ float rcs[PB];

    const int tid   = threadIdx.x;
    const int cbase = blockIdx.y * 64;

    for (int s = tid; s < 128 * 64; s += 256) {
        const int k = s >> 6, c = s & 63;
        w2[k][c] = Wf2[k * 128 + cbase + c];
    }
    for (int s = tid; s < RDIM * 128; s += 256)
        wf1[s] = Wf1[s];

    const int pg     = tid >> 4;   // 0..15 : pair group (4 pairs)
    const int cg     = tid & 15;   // 0..15 : col group  (4 cols)
    const int p_lane = tid & 63;   // phase-A pair index
    const int kq     = tid >> 6;   // phase-A k quarter (wave-uniform)

    for (int chunk = blockIdx.x; chunk < NCHUNK; chunk += gridDim.x) {
        const int pbase = chunk * PB;
        for (int s = tid; s < PB * RDIM; s += 256)
            fst[s / RDIM][s % RDIM] = f_ij[pbase * RDIM + s];
        if (tid < PB) {
            iis[tid] = idx_i[pbase + tid];
            jjs[tid] = idx_j[pbase + tid];
            rcs[tid] = rcut[pbase + tid];
        }

        float acc[4][4];
        #pragma unroll
        for (int i = 0; i < 4; ++i)
            #pragma unroll
            for (int j = 0; j < 4; ++j) acc[i][j] = 0.0f;

        for (int kt = 0; kt < 4; ++kt) {
            __syncthreads();   // staging done (kt=0) / prev phase-B readers done
            // ---- phase A: act[k] = ssp(f @ Wf1 + bf1) for 32 k's ----
            #pragma unroll
            for (int q = 0; q < 8; ++q) {
                const int kl = kq * 8 + q;
                const int k  = kt * 32 + kl;
                float a = bf1[k];
                #pragma unroll
                for (int r = 0; r < RDIM; ++r)
                    a = fmaf(fst[p_lane][r], wf1[r * 128 + k], a);
                act[kl][p_lane] = sspf(a);
            }
            __syncthreads();
            // ---- phase B: acc += act_tile^T segment @ Wf2 half ----
            #pragma unroll
            for (int kk = 0; kk < 32; ++kk) {
                const float4 a4 = *(const float4*)&act[kk][pg << 2];
                const float4 w4 = *(const float4*)&w2[kt * 32 + kk][cg << 2];
                acc[0][0] = fmaf(a4.x, w4.x, acc[0][0]);
                acc[0][1] = fmaf(a4.x, w4.y, acc[0][1]);
                acc[0][2] = fmaf(a4.x, w4.z, acc[0][2]);
                acc[0][3] = fmaf(a4.x, w4.w, acc[0][3]);
                acc[1][0] = fmaf(a4.y, w4.x, acc[1][0]);
                acc[1][1] = fmaf(a4.y, w4.y, acc[1][1]);
                acc[1][2] = fmaf(a4.y, w4.z, acc[1][2]);
                acc[1][3] = fmaf(a4.y, w4.w, acc[1][3]);
                acc[2][0] = fmaf(a4.z, w4.x, acc[2][0]);
                acc[2][1] = fmaf(a4.z, w4.y, acc[2][1]);
                acc[2][2] = fmaf(a4.z, w4.z, acc[2][2]);
                acc[2][3] = fmaf(a4.z, w4.w, acc[2][3]);
                acc[3][0] = fmaf(a4.w, w4.x, acc[3][0]);
                acc[3][1] = fmaf(a4.w, w4.y, acc[3][1]);
                acc[3][2] = fmaf(a4.w, w4.z, acc[3][2]);
                acc[3][3] = fmaf(a4.w, w4.w, acc[3][3]);
            }
        }

        // ---- epilogue: Wij = (acc + bf2)*rcut; scatter h[j]*Wij into agg[i] ----
        const float4 b2 = *(const float4*)&bf2[cbase + (cg << 2)];
        #pragma unroll
        for (int i = 0; i < 4; ++i) {
            const int p  = (pg << 2) + i;
            const int gi = iis[p];
            const int gj = jjs[p];
            const float r = rcs[p];
            const float4 hv = *(const float4*)&h[gj * 128 + cbase + (cg << 2)];
            float* dst = &agg[gi * 128 + cbase + (cg << 2)];
            unsafeAtomicAdd(dst + 0, hv.x * ((acc[i][0] + b2.x) * r));
            unsafeAtomicAdd(dst + 1, hv.y * ((acc[i][1] + b2.y) * r));
            unsafeAtomicAdd(dst + 2, hv.z * ((acc[i][2] + b2.z) * r));
            unsafeAtomicAdd(dst + 3, hv.w * ((acc[i][3] + b2.w) * r));
        }
        __syncthreads();   // protect iis/jjs/rcs/fst before next chunk staging
    }
}

extern "C" void kernel_launch(void* const* d_in, const int* in_sizes, int n_in,
                              void* d_out, int out_size, void* d_ws, size_t ws_size,
                              hipStream_t stream) {
    const float* x     = (const float*)d_in[0];
    const float* f_ij  = (const float*)d_in[1];
    const int*   idx_i = (const int*)  d_in[2];
    const int*   idx_j = (const int*)  d_in[3];
    const float* rcut  = (const float*)d_in[4];
    const float* W_in  = (const float*)d_in[5];
    const float* b_in  = (const float*)d_in[6];
    const float* Wf1   = (const float*)d_in[7];
    const float* bf1   = (const float*)d_in[8];
    const float* Wf2   = (const float*)d_in[9];
    const float* bf2   = (const float*)d_in[10];
    const float* Wo1   = (const float*)d_in[11];
    const float* bo1   = (const float*)d_in[12];
    const float* Wo2   = (const float*)d_in[13];
    const float* bo2   = (const float*)d_in[14];
    float* out = (float*)d_out;

    const size_t AGG_BYTES = (size_t)BN * FDIM * sizeof(float);  // 4,096,000
    float* agg = (float*)d_ws;
    float* h   = (float*)((char*)d_ws + AGG_BYTES);
    float* t1  = (float*)((char*)d_ws + 2 * AGG_BYTES);

    hipMemsetAsync(agg, 0, AGG_BYTES, stream);

    // h = x @ W_in + b_in
    rowgemm_kernel<false><<<BN / 16, 256, 0, stream>>>(x, W_in, b_in, h);

    // filter net + gather/scatter into agg
    pairs_kernel<<<dim3(2000, 2), 256, 0, stream>>>(
        f_ij, idx_i, idx_j, rcut, Wf1, bf1, Wf2, bf2, h, agg);

    // out = ssp(agg @ Wo1 + bo1) @ Wo2 + bo2
    rowgemm_kernel<true><<<BN / 16, 256, 0, stream>>>(agg, Wo1, bo1, t1);
    rowgemm_kernel<false><<<BN / 16, 256, 0, stream>>>(t1, Wo2, bo2, out);
}

// Round 2
// 904.782 us; speedup vs baseline: 1.3709x; 1.3709x over previous
//
#include <hip/hip_runtime.h>
#include <math.h>

#define FDIM 128
#define RDIM 20
#define BN   8000
#define NPAIR 512000
#define PB   64
#define NCHUNK (NPAIR/PB)
#define PAIRS_GRID 2048

typedef __attribute__((ext_vector_type(8))) short short8v;
typedef __attribute__((ext_vector_type(4))) float float4v;

// fast ShiftedSoftplus: max(x,0) + log(1+exp(-|x|)) - ln2, fast intrinsics
__device__ __forceinline__ float sspf_fast(float x) {
    return fmaxf(x, 0.0f) + __logf(1.0f + __expf(-fabsf(x))) - 0.69314718055994531f;
}
// precise version for the small row-GEMMs (cheap there)
__device__ __forceinline__ float sspf(float x) {
    return fmaxf(x, 0.0f) + log1pf(expf(-fabsf(x))) - 0.69314718055994531f;
}

__device__ __forceinline__ unsigned short f2bf(float x) {
    union { float f; unsigned u; } v; v.f = x;
    unsigned r = (v.u + 0x7FFFu + ((v.u >> 16) & 1u)) >> 16;
    return (unsigned short)r;
}

// ---------------------------------------------------------------------------
// C[p, :] = act(A[p, :] @ W + bias), 16 rows per block, 256 threads.
template<bool SSP>
__global__ __launch_bounds__(256) void rowgemm_kernel(
    const float* __restrict__ A, const float* __restrict__ W,
    const float* __restrict__ bias, float* __restrict__ C)
{
    __shared__ float rowlds[16 * 128];
    const int tid = threadIdx.x;
    const int blk = blockIdx.x;
    for (int s = tid; s < 16 * 128; s += 256)
        rowlds[s] = A[blk * 16 * 128 + s];
    __syncthreads();

    const int lane = tid & 63;
    const int wave = tid >> 6;
    const float b0 = bias[lane];
    const float b1 = bias[64 + lane];
    float acc[4][2];
    #pragma unroll
    for (int rr = 0; rr < 4; ++rr) { acc[rr][0] = b0; acc[rr][1] = b1; }

    #pragma unroll 4
    for (int m = 0; m < 128; ++m) {
        const float w0 = W[m * 128 + lane];
        const float w1 = W[m * 128 + 64 + lane];
        #pragma unroll
        for (int rr = 0; rr < 4; ++rr) {
            const float av = rowlds[(wave * 4 + rr) * 128 + m];
            acc[rr][0] = fmaf(av, w0, acc[rr][0]);
            acc[rr][1] = fmaf(av, w1, acc[rr][1]);
        }
    }

    #pragma unroll
    for (int rr = 0; rr < 4; ++rr) {
        const int p = blk * 16 + wave * 4 + rr;
        float v0 = acc[rr][0], v1 = acc[rr][1];
        if (SSP) { v0 = sspf(v0); v1 = sspf(v1); }
        C[p * 128 + lane]      = v0;
        C[p * 128 + 64 + lane] = v1;
    }
}

// ---------------------------------------------------------------------------
// MFMA pairs kernel, transposed form.
// Layer 1: act_pre^T = Wf1^T(A, regs) x f^T(B, LDS), K=32 (pad 20).
// Layer 2: Wij^T    = Wf2^T(A, regs) x act^T(B, LDS swizzled), K=128.
// Epilogue: Wij=(acc+bf2)*rcut, atomicAdd h[idx_j]*Wij into agg[idx_i].
__global__ __launch_bounds__(256) void pairs_mfma(
    const float* __restrict__ f_ij, const int* __restrict__ idx_i,
    const int* __restrict__ idx_j, const float* __restrict__ rcut,
    const float* __restrict__ Wf1, const float* __restrict__ bf1,
    const float* __restrict__ Wf2, const float* __restrict__ bf2,
    const float* __restrict__ h, float* __restrict__ agg)
{
    __shared__ unsigned short act[64 * 128];   // bf16, row stride 256B, XOR-swizzled
    __shared__ unsigned short fbuf[64 * 64];   // bf16, row stride 128B, XOR-swizzled, k padded to 32
    __shared__ int   iis[PB];
    __shared__ int   jjs[PB];
    __shared__ float rcs[PB];

    const int tid = threadIdx.x;
    const int w   = tid >> 6;       // wave 0..3: owns out-cols [w*32, w*32+32)
    const int l   = tid & 63;
    const int l15 = l & 15;         // row-in-tile / col-in-tile
    const int l4  = l >> 4;         // k-octet group
    const int swz = (l15 & 7) << 4; // byte-XOR swizzle within a row

    // ---- per-block setup: weight fragments in registers ----
    // Layer-1 A frags: A1[m][k] = Wf1[k][w*32 + kt2*16 + m]  (k>=20 -> 0)
    short8v wf1a[2];
    #pragma unroll
    for (int kt2 = 0; kt2 < 2; ++kt2) {
        const int ck = w * 32 + kt2 * 16 + l15;
        #pragma unroll
        for (int e = 0; e < 8; ++e) {
            const int r = l4 * 8 + e;
            const float val = (r < RDIM) ? Wf1[r * 128 + ck] : 0.0f;
            wf1a[kt2][e] = (short)f2bf(val);
        }
    }
    // Layer-2 A frags: A2[m][k] = Wf2[ks*32 + l4*8 + e][w*32 + mt*16 + m]
    short8v wf2a[2][4];
    #pragma unroll
    for (int mt = 0; mt < 2; ++mt) {
        const int c = w * 32 + mt * 16 + l15;
        #pragma unroll
        for (int ks = 0; ks < 4; ++ks) {
            #pragma unroll
            for (int e = 0; e < 8; ++e) {
                const int k = ks * 32 + l4 * 8 + e;
                wf2a[mt][ks][e] = (short)f2bf(Wf2[k * 128 + c]);
            }
        }
    }
    float b1v[2][4], b2v[2][4];
    #pragma unroll
    for (int t = 0; t < 2; ++t)
        #pragma unroll
        for (int j = 0; j < 4; ++j) {
            b1v[t][j] = bf1[w * 32 + t * 16 + l4 * 4 + j];
            b2v[t][j] = bf2[w * 32 + t * 16 + l4 * 4 + j];
        }

    // zero-fill fbuf pad region (k in [20,32)) once; never rewritten
    for (int s = tid; s < 64 * (32 - RDIM); s += 256) {
        const int p = s / (32 - RDIM);
        const int k = RDIM + s % (32 - RDIM);
        const int byte = p * 128 + ((k * 2) ^ ((p & 7) << 4));
        fbuf[byte >> 1] = 0;
    }

    for (int chunk = blockIdx.x; chunk < NCHUNK; chunk += PAIRS_GRID) {
        const int pbase = chunk * PB;
        __syncthreads();   // prev chunk done reading fbuf (L1) and act (L2)

        // ---- stage f chunk (fp32 -> bf16, swizzled) + indices ----
        #pragma unroll
        for (int i = 0; i < 5; ++i) {
            const int s = tid + i * 256;            // 0..1279
            const int p = s / RDIM, k = s % RDIM;
            const float val = f_ij[(size_t)pbase * RDIM + s];
            const int byte = p * 128 + ((k * 2) ^ ((p & 7) << 4));
            fbuf[byte >> 1] = f2bf(val);
        }
        if (tid < PB) {
            iis[tid] = idx_i[pbase + tid];
            jjs[tid] = idx_j[pbase + tid];
            rcs[tid] = rcut[pbase + tid];
        }
        __syncthreads();   // fbuf/idx ready

        // ---- layer 1: act_pre^T = Wf1^T x f^T, then ssp -> act (bf16, LDS) ----
        short8v ffr[4];
        #pragma unroll
        for (int nt = 0; nt < 4; ++nt) {
            const int row = nt * 16 + l15;
            const int byte = row * 128 + ((l4 * 16) ^ swz);
            ffr[nt] = *(const short8v*)((const char*)fbuf + byte);
        }
        #pragma unroll
        for (int kt2 = 0; kt2 < 2; ++kt2) {
            #pragma unroll
            for (int nt = 0; nt < 4; ++nt) {
                float4v acc1 = {0.f, 0.f, 0.f, 0.f};
                acc1 = __builtin_amdgcn_mfma_f32_16x16x32_bf16(wf1a[kt2], ffr[nt], acc1, 0, 0, 0);
                // lane holds act_pre[pair = nt*16+l15][kout = w*32+kt2*16+l4*4+j]
                unsigned short pk[4];
                #pragma unroll
                for (int j = 0; j < 4; ++j)
                    pk[j] = f2bf(sspf_fast(acc1[j] + b1v[kt2][j]));
                const int row = nt * 16 + l15;
                const int byte = row * 256 + ((w * 64 + kt2 * 32 + l4 * 8) ^ swz);
                *(unsigned long long*)((char*)act + byte) =
                    (unsigned long long)pk[0] | ((unsigned long long)pk[1] << 16) |
                    ((unsigned long long)pk[2] << 32) | ((unsigned long long)pk[3] << 48);
            }
        }
        __syncthreads();   // act ready

        // ---- layer 2: Wij^T = Wf2^T x act^T ----
        float4v a2[2][4];
        #pragma unroll
        for (int mt = 0; mt < 2; ++mt)
            #pragma unroll
            for (int nt = 0; nt < 4; ++nt)
                a2[mt][nt] = float4v{0.f, 0.f, 0.f, 0.f};

        #pragma unroll
        for (int ks = 0; ks < 4; ++ks) {
            short8v bfr[4];
            #pragma unroll
            for (int nt = 0; nt < 4; ++nt) {
                const int row = nt * 16 + l15;
                const int byte = row * 256 + ((ks * 64 + l4 * 16) ^ swz);
                bfr[nt] = *(const short8v*)((const char*)act + byte);
            }
            #pragma unroll
            for (int mt = 0; mt < 2; ++mt)
                #pragma unroll
                for (int nt = 0; nt < 4; ++nt)
                    a2[mt][nt] = __builtin_amdgcn_mfma_f32_16x16x32_bf16(
                        wf2a[mt][ks], bfr[nt], a2[mt][nt], 0, 0, 0);
        }

        // ---- epilogue: Wij = (acc+bf2)*rcut; scatter h[j]*Wij into agg[i] ----
        #pragma unroll
        for (int nt = 0; nt < 4; ++nt) {
            const int p  = nt * 16 + l15;
            const int gi = iis[p] * 128;
            const int gj = jjs[p] * 128;
            const float r = rcs[p];
            #pragma unroll
            for (int mt = 0; mt < 2; ++mt) {
                const int cb = w * 32 + mt * 16 + l4 * 4;
                const float4 hv = *(const float4*)&h[gj + cb];
                float* dst = &agg[gi + cb];
                unsafeAtomicAdd(dst + 0, hv.x * ((a2[mt][nt][0] + b2v[mt][0]) * r));
                unsafeAtomicAdd(dst + 1, hv.y * ((a2[mt][nt][1] + b2v[mt][1]) * r));
                unsafeAtomicAdd(dst + 2, hv.z * ((a2[mt][nt][2] + b2v[mt][2]) * r));
                unsafeAtomicAdd(dst + 3, hv.w * ((a2[mt][nt][3] + b2v[mt][3]) * r));
            }
        }
    }
}

extern "C" void kernel_launch(void* const* d_in, const int* in_sizes, int n_in,
                              void* d_out, int out_size, void* d_ws, size_t ws_size,
                              hipStream_t stream) {
    const float* x     = (const float*)d_in[0];
    const float* f_ij  = (const float*)d_in[1];
    const int*   idx_i = (const int*)  d_in[2];
    const int*   idx_j = (const int*)  d_in[3];
    const float* rcut  = (const float*)d_in[4];
    const float* W_in  = (const float*)d_in[5];
    const float* b_in  = (const float*)d_in[6];
    const float* Wf1   = (const float*)d_in[7];
    const float* bf1   = (const float*)d_in[8];
    const float* Wf2   = (const float*)d_in[9];
    const float* bf2   = (const float*)d_in[10];
    const float* Wo1   = (const float*)d_in[11];
    const float* bo1   = (const float*)d_in[12];
    const float* Wo2   = (const float*)d_in[13];
    const float* bo2   = (const float*)d_in[14];
    float* out = (float*)d_out;

    const size_t AGG_BYTES = (size_t)BN * FDIM * sizeof(float);  // 4,096,000
    float* agg = (float*)d_ws;
    float* h   = (float*)((char*)d_ws + AGG_BYTES);
    float* t1  = (float*)((char*)d_ws + 2 * AGG_BYTES);

    hipMemsetAsync(agg, 0, AGG_BYTES, stream);

    // h = x @ W_in + b_in
    rowgemm_kernel<false><<<BN / 16, 256, 0, stream>>>(x, W_in, b_in, h);

    // filter net (MFMA) + gather/scatter into agg
    pairs_mfma<<<PAIRS_GRID, 256, 0, stream>>>(
        f_ij, idx_i, idx_j, rcut, Wf1, bf1, Wf2, bf2, h, agg);

    // out = ssp(agg @ Wo1 + bo1) @ Wo2 + bo2
    rowgemm_kernel<true><<<BN / 16, 256, 0, stream>>>(agg, Wo1, bo1, t1);
    rowgemm_kernel<false><<<BN / 16, 256, 0, stream>>>(t1, Wo2, bo2, out);
}

// Round 3
// 654.892 us; speedup vs baseline: 1.8940x; 1.3816x over previous
//
#include <hip/hip_runtime.h>
#include <math.h>

#define FDIM 128
#define RDIM 20
#define BN   8000
#define NPAIR 512000
#define PB   64

typedef __attribute__((ext_vector_type(8))) short short8v;
typedef __attribute__((ext_vector_type(4))) float float4v;

// fast ShiftedSoftplus: max(x,0) + log(1+exp(-|x|)) - ln2, fast intrinsics
__device__ __forceinline__ float sspf_fast(float x) {
    return fmaxf(x, 0.0f) + __logf(1.0f + __expf(-fabsf(x))) - 0.69314718055994531f;
}
// precise version for the small row-GEMMs (cheap there)
__device__ __forceinline__ float sspf(float x) {
    return fmaxf(x, 0.0f) + log1pf(expf(-fabsf(x))) - 0.69314718055994531f;
}

__device__ __forceinline__ unsigned short f2bf(float x) {
    union { float f; unsigned u; } v; v.f = x;
    unsigned r = (v.u + 0x7FFFu + ((v.u >> 16) & 1u)) >> 16;
    return (unsigned short)r;
}

// ---------------------------------------------------------------------------
// CSR preprocessing: histogram -> exclusive scan -> stable-ish scatter
__global__ __launch_bounds__(256) void hist_kernel(
    const int* __restrict__ idx_i, int* __restrict__ cnt)
{
    const int p = blockIdx.x * 256 + threadIdx.x;
    if (p < NPAIR) atomicAdd(&cnt[idx_i[p]], 1);
}

// single block, 1024 threads, 8 elems each. cursor[i] = exclusive prefix.
__global__ __launch_bounds__(1024) void scan_kernel(
    const int* __restrict__ cnt, int* __restrict__ cursor)
{
    __shared__ int part[1024];
    const int t = threadIdx.x;
    int v[8]; int sum = 0;
    #pragma unroll
    for (int k = 0; k < 8; ++k) {
        const int i = t * 8 + k;
        const int c = (i < BN) ? cnt[i] : 0;
        v[k] = sum; sum += c;
    }
    part[t] = sum;
    __syncthreads();
    for (int off = 1; off < 1024; off <<= 1) {
        const int x = (t >= off) ? part[t - off] : 0;
        __syncthreads();
        part[t] += x;
        __syncthreads();
    }
    const int base = (t == 0) ? 0 : part[t - 1];
    #pragma unroll
    for (int k = 0; k < 8; ++k) {
        const int i = t * 8 + k;
        if (i < BN) cursor[i] = base + v[k];
    }
}

// after this kernel cursor[r] = end offset of row r's segment
__global__ __launch_bounds__(256) void scatter_kernel(
    const int* __restrict__ idx_i, int* __restrict__ cursor, int* __restrict__ perm)
{
    const int p = blockIdx.x * 256 + threadIdx.x;
    if (p < NPAIR) {
        const int pos = atomicAdd(&cursor[idx_i[p]], 1);
        perm[pos] = p;
    }
}

// ---------------------------------------------------------------------------
// C[p, :] = act(A[p, :] @ W + bias), 16 rows per block, 256 threads.
template<bool SSP>
__global__ __launch_bounds__(256) void rowgemm_kernel(
    const float* __restrict__ A, const float* __restrict__ W,
    const float* __restrict__ bias, float* __restrict__ C)
{
    __shared__ float rowlds[16 * 128];
    const int tid = threadIdx.x;
    const int blk = blockIdx.x;
    for (int s = tid; s < 16 * 128; s += 256)
        rowlds[s] = A[blk * 16 * 128 + s];
    __syncthreads();

    const int lane = tid & 63;
    const int wave = tid >> 6;
    const float b0 = bias[lane];
    const float b1 = bias[64 + lane];
    float acc[4][2];
    #pragma unroll
    for (int rr = 0; rr < 4; ++rr) { acc[rr][0] = b0; acc[rr][1] = b1; }

    #pragma unroll 4
    for (int m = 0; m < 128; ++m) {
        const float w0 = W[m * 128 + lane];
        const float w1 = W[m * 128 + 64 + lane];
        #pragma unroll
        for (int rr = 0; rr < 4; ++rr) {
            const float av = rowlds[(wave * 4 + rr) * 128 + m];
            acc[rr][0] = fmaf(av, w0, acc[rr][0]);
            acc[rr][1] = fmaf(av, w1, acc[rr][1]);
        }
    }

    #pragma unroll
    for (int rr = 0; rr < 4; ++rr) {
        const int p = blk * 16 + wave * 4 + rr;
        float v0 = acc[rr][0], v1 = acc[rr][1];
        if (SSP) { v0 = sspf(v0); v1 = sspf(v1); }
        C[p * 128 + lane]      = v0;
        C[p * 128 + 64 + lane] = v1;
    }
}

// ---------------------------------------------------------------------------
// Row-centric MFMA pairs kernel over CSR-sorted pairs.
// Block b owns rows [b*16, b*16+16); accumulates into LDS, no global atomics.
__global__ __launch_bounds__(256) void pairs_sorted(
    const float* __restrict__ f_ij, const int* __restrict__ idx_i,
    const int* __restrict__ idx_j, const float* __restrict__ rcut,
    const float* __restrict__ Wf1, const float* __restrict__ bf1,
    const float* __restrict__ Wf2, const float* __restrict__ bf2,
    const float* __restrict__ h, const int* __restrict__ rowEnd,
    const int* __restrict__ perm, float* __restrict__ agg)
{
    __shared__ unsigned short act[64 * 128];   // bf16, row stride 256B, XOR-swizzled
    __shared__ unsigned short fbuf[64 * 64];   // bf16, row stride 128B, swizzled, k padded to 32
    __shared__ float accT[16 * 132];           // fp32 row accumulator, padded stride
    __shared__ int   rrs[PB];
    __shared__ int   jjs[PB];
    __shared__ float rcs[PB];

    const int tid = threadIdx.x;
    const int w   = tid >> 6;       // wave 0..3: owns out-cols [w*32, w*32+32)
    const int l   = tid & 63;
    const int l15 = l & 15;
    const int l4  = l >> 4;
    const int swz = (l15 & 7) << 4;

    const int row0 = blockIdx.x * 16;
    const int s0 = (row0 == 0) ? 0 : rowEnd[row0 - 1];
    const int s1 = rowEnd[row0 + 15];

    // ---- weight fragments in registers (same layout as round 2) ----
    short8v wf1a[2];
    #pragma unroll
    for (int kt2 = 0; kt2 < 2; ++kt2) {
        const int ck = w * 32 + kt2 * 16 + l15;
        #pragma unroll
        for (int e = 0; e < 8; ++e) {
            const int r = l4 * 8 + e;
            const float val = (r < RDIM) ? Wf1[r * 128 + ck] : 0.0f;
            wf1a[kt2][e] = (short)f2bf(val);
        }
    }
    short8v wf2a[2][4];
    #pragma unroll
    for (int mt = 0; mt < 2; ++mt) {
        const int c = w * 32 + mt * 16 + l15;
        #pragma unroll
        for (int ks = 0; ks < 4; ++ks) {
            #pragma unroll
            for (int e = 0; e < 8; ++e) {
                const int k = ks * 32 + l4 * 8 + e;
                wf2a[mt][ks][e] = (short)f2bf(Wf2[k * 128 + c]);
            }
        }
    }
    float b1v[2][4], b2v[2][4];
    #pragma unroll
    for (int t = 0; t < 2; ++t)
        #pragma unroll
        for (int j = 0; j < 4; ++j) {
            b1v[t][j] = bf1[w * 32 + t * 16 + l4 * 4 + j];
            b2v[t][j] = bf2[w * 32 + t * 16 + l4 * 4 + j];
        }

    // zero LDS accumulator
    for (int sidx = tid; sidx < 16 * 132; sidx += 256) accT[sidx] = 0.0f;
    // zero-fill fbuf pad region (k in [20,32)) once
    for (int sidx = tid; sidx < 64 * (32 - RDIM); sidx += 256) {
        const int p = sidx / (32 - RDIM);
        const int k = RDIM + sidx % (32 - RDIM);
        const int byte = p * 128 + ((k * 2) ^ ((p & 7) << 4));
        fbuf[byte >> 1] = 0;
    }

    for (int s = s0; s < s1; s += PB) {
        __syncthreads();   // prev chunk fully consumed (incl. epilogue reads of rrs/jjs)

        // ---- stage sorted-pair metadata + f rows (gathered via perm) ----
        if (tid < PB) {
            const int q  = s + tid;
            const int qc = q < s1 ? q : s1 - 1;
            const int pid = perm[qc];
            rrs[tid] = idx_i[pid] - row0;            // in [0,16)
            jjs[tid] = idx_j[pid];
            rcs[tid] = (q < s1) ? rcut[pid] : 0.0f;  // pad slots contribute 0
        }
        #pragma unroll
        for (int i = 0; i < 5; ++i) {
            const int sidx = tid + i * 256;          // 0..1279
            const int p = sidx / RDIM, k = sidx % RDIM;
            const int q = s + p;
            const int pid = perm[q < s1 ? q : s1 - 1];
            const float val = f_ij[(size_t)pid * RDIM + k];
            const int byte = p * 128 + ((k * 2) ^ ((p & 7) << 4));
            fbuf[byte >> 1] = f2bf(val);
        }
        __syncthreads();   // fbuf + metadata ready

        // ---- layer 1: act_pre^T = Wf1^T x f^T, ssp -> act (bf16, LDS) ----
        short8v ffr[4];
        #pragma unroll
        for (int nt = 0; nt < 4; ++nt) {
            const int row = nt * 16 + l15;
            const int byte = row * 128 + ((l4 * 16) ^ swz);
            ffr[nt] = *(const short8v*)((const char*)fbuf + byte);
        }
        #pragma unroll
        for (int kt2 = 0; kt2 < 2; ++kt2) {
            #pragma unroll
            for (int nt = 0; nt < 4; ++nt) {
                float4v acc1 = {0.f, 0.f, 0.f, 0.f};
                acc1 = __builtin_amdgcn_mfma_f32_16x16x32_bf16(wf1a[kt2], ffr[nt], acc1, 0, 0, 0);
                unsigned short pk[4];
                #pragma unroll
                for (int j = 0; j < 4; ++j)
                    pk[j] = f2bf(sspf_fast(acc1[j] + b1v[kt2][j]));
                const int row = nt * 16 + l15;
                const int byte = row * 256 + ((w * 64 + kt2 * 32 + l4 * 8) ^ swz);
                *(unsigned long long*)((char*)act + byte) =
                    (unsigned long long)pk[0] | ((unsigned long long)pk[1] << 16) |
                    ((unsigned long long)pk[2] << 32) | ((unsigned long long)pk[3] << 48);
            }
        }
        __syncthreads();   // act ready

        // ---- layer 2: Wij^T = Wf2^T x act^T ----
        float4v a2[2][4];
        #pragma unroll
        for (int mt = 0; mt < 2; ++mt)
            #pragma unroll
            for (int nt = 0; nt < 4; ++nt)
                a2[mt][nt] = float4v{0.f, 0.f, 0.f, 0.f};

        #pragma unroll
        for (int ks = 0; ks < 4; ++ks) {
            short8v bfr[4];
            #pragma unroll
            for (int nt = 0; nt < 4; ++nt) {
                const int row = nt * 16 + l15;
                const int byte = row * 256 + ((ks * 64 + l4 * 16) ^ swz);
                bfr[nt] = *(const short8v*)((const char*)act + byte);
            }
            #pragma unroll
            for (int mt = 0; mt < 2; ++mt)
                #pragma unroll
                for (int nt = 0; nt < 4; ++nt)
                    a2[mt][nt] = __builtin_amdgcn_mfma_f32_16x16x32_bf16(
                        wf2a[mt][ks], bfr[nt], a2[mt][nt], 0, 0, 0);
        }

        // ---- epilogue: accT[row][col] += h[idx_j][col] * Wij  (LDS atomics) ----
        #pragma unroll
        for (int nt = 0; nt < 4; ++nt) {
            const int p  = nt * 16 + l15;
            const int rr = rrs[p];
            const int gj = jjs[p] * 128;
            const float r = rcs[p];
            #pragma unroll
            for (int mt = 0; mt < 2; ++mt) {
                const int cb = w * 32 + mt * 16 + l4 * 4;
                const float4 hv = *(const float4*)&h[gj + cb];
                float* dst = &accT[rr * 132 + cb];
                atomicAdd(dst + 0, hv.x * ((a2[mt][nt][0] + b2v[mt][0]) * r));
                atomicAdd(dst + 1, hv.y * ((a2[mt][nt][1] + b2v[mt][1]) * r));
                atomicAdd(dst + 2, hv.z * ((a2[mt][nt][2] + b2v[mt][2]) * r));
                atomicAdd(dst + 3, hv.w * ((a2[mt][nt][3] + b2v[mt][3]) * r));
            }
        }
    }

    // ---- write out this block's 16 rows (plain coalesced stores) ----
    __syncthreads();
    for (int sidx = tid; sidx < 16 * 128; sidx += 256) {
        const int r = sidx >> 7, c = sidx & 127;
        agg[(size_t)(row0 + r) * 128 + c] = accT[r * 132 + c];
    }
}

extern "C" void kernel_launch(void* const* d_in, const int* in_sizes, int n_in,
                              void* d_out, int out_size, void* d_ws, size_t ws_size,
                              hipStream_t stream) {
    const float* x     = (const float*)d_in[0];
    const float* f_ij  = (const float*)d_in[1];
    const int*   idx_i = (const int*)  d_in[2];
    const int*   idx_j = (const int*)  d_in[3];
    const float* rcut  = (const float*)d_in[4];
    const float* W_in  = (const float*)d_in[5];
    const float* b_in  = (const float*)d_in[6];
    const float* Wf1   = (const float*)d_in[7];
    const float* bf1   = (const float*)d_in[8];
    const float* Wf2   = (const float*)d_in[9];
    const float* bf2   = (const float*)d_in[10];
    const float* Wo1   = (const float*)d_in[11];
    const float* bo1   = (const float*)d_in[12];
    const float* Wo2   = (const float*)d_in[13];
    const float* bo2   = (const float*)d_in[14];
    float* out = (float*)d_out;

    const size_t SLAB = (size_t)BN * FDIM * sizeof(float);  // 4,096,000
    float* h   = (float*)d_ws;
    float* t1  = (float*)((char*)d_ws + SLAB);
    float* agg = (float*)((char*)d_ws + 2 * SLAB);
    // CSR scratch overlaid on t1 (t1 is only live after pairs_sorted)
    int* perm   = (int*)t1;                                   // 512000 ints
    int* cnt    = (int*)((char*)t1 + (size_t)NPAIR * 4);      // 8001 ints
    int* cursor = cnt + 8001;                                 // 8000 ints

    // CSR sort of pairs by idx_i
    hipMemsetAsync(cnt, 0, (BN + 1) * sizeof(int), stream);
    hist_kernel<<<NPAIR / 256, 256, 0, stream>>>(idx_i, cnt);
    scan_kernel<<<1, 1024, 0, stream>>>(cnt, cursor);
    scatter_kernel<<<NPAIR / 256, 256, 0, stream>>>(idx_i, cursor, perm);

    // h = x @ W_in + b_in
    rowgemm_kernel<false><<<BN / 16, 256, 0, stream>>>(x, W_in, b_in, h);

    // filter net (MFMA) + gather + row-local aggregation
    pairs_sorted<<<BN / 16, 256, 0, stream>>>(
        f_ij, idx_i, idx_j, rcut, Wf1, bf1, Wf2, bf2, h, cursor, perm, agg);

    // out = ssp(agg @ Wo1 + bo1) @ Wo2 + bo2
    rowgemm_kernel<true><<<BN / 16, 256, 0, stream>>>(agg, Wo1, bo1, t1);
    rowgemm_kernel<false><<<BN / 16, 256, 0, stream>>>(t1, Wo2, bo2, out);
}

// Round 4
// 231.773 us; speedup vs baseline: 5.3515x; 2.8256x over previous
//
#include <hip/hip_runtime.h>
#include <math.h>

#define FDIM 128
#define RDIM 20
#define BN   8000
#define NPAIR 512000
#define PB   64

typedef __attribute__((ext_vector_type(8))) short short8v;
typedef __attribute__((ext_vector_type(4))) float float4v;

// fast ShiftedSoftplus: max(x,0) + log(1+exp(-|x|)) - ln2, fast intrinsics
__device__ __forceinline__ float sspf_fast(float x) {
    return fmaxf(x, 0.0f) + __logf(1.0f + __expf(-fabsf(x))) - 0.69314718055994531f;
}
// precise version for the small row-GEMMs (cheap there)
__device__ __forceinline__ float sspf(float x) {
    return fmaxf(x, 0.0f) + log1pf(expf(-fabsf(x))) - 0.69314718055994531f;
}

__device__ __forceinline__ unsigned short f2bf(float x) {
    union { float f; unsigned u; } v; v.f = x;
    unsigned r = (v.u + 0x7FFFu + ((v.u >> 16) & 1u)) >> 16;
    return (unsigned short)r;
}

// ---------------------------------------------------------------------------
// CSR preprocessing: histogram -> exclusive scan -> scatter
__global__ __launch_bounds__(256) void hist_kernel(
    const int* __restrict__ idx_i, int* __restrict__ cnt)
{
    const int p = blockIdx.x * 256 + threadIdx.x;
    if (p < NPAIR) atomicAdd(&cnt[idx_i[p]], 1);
}

__global__ __launch_bounds__(1024) void scan_kernel(
    const int* __restrict__ cnt, int* __restrict__ cursor)
{
    __shared__ int part[1024];
    const int t = threadIdx.x;
    int v[8]; int sum = 0;
    #pragma unroll
    for (int k = 0; k < 8; ++k) {
        const int i = t * 8 + k;
        const int c = (i < BN) ? cnt[i] : 0;
        v[k] = sum; sum += c;
    }
    part[t] = sum;
    __syncthreads();
    for (int off = 1; off < 1024; off <<= 1) {
        const int x = (t >= off) ? part[t - off] : 0;
        __syncthreads();
        part[t] += x;
        __syncthreads();
    }
    const int base = (t == 0) ? 0 : part[t - 1];
    #pragma unroll
    for (int k = 0; k < 8; ++k) {
        const int i = t * 8 + k;
        if (i < BN) cursor[i] = base + v[k];
    }
}

// after this kernel cursor[r] = end offset of row r's segment
__global__ __launch_bounds__(256) void scatter_kernel(
    const int* __restrict__ idx_i, int* __restrict__ cursor, int* __restrict__ perm)
{
    const int p = blockIdx.x * 256 + threadIdx.x;
    if (p < NPAIR) {
        const int pos = atomicAdd(&cursor[idx_i[p]], 1);
        perm[pos] = p;
    }
}

// ---------------------------------------------------------------------------
// C[p, :] = act(A[p, :] @ W + bias), 16 rows per block, 256 threads.
template<bool SSP>
__global__ __launch_bounds__(256) void rowgemm_kernel(
    const float* __restrict__ A, const float* __restrict__ W,
    const float* __restrict__ bias, float* __restrict__ C)
{
    __shared__ float rowlds[16 * 128];
    const int tid = threadIdx.x;
    const int blk = blockIdx.x;
    for (int s = tid; s < 16 * 128; s += 256)
        rowlds[s] = A[blk * 16 * 128 + s];
    __syncthreads();

    const int lane = tid & 63;
    const int wave = tid >> 6;
    const float b0 = bias[lane];
    const float b1 = bias[64 + lane];
    float acc[4][2];
    #pragma unroll
    for (int rr = 0; rr < 4; ++rr) { acc[rr][0] = b0; acc[rr][1] = b1; }

    #pragma unroll 4
    for (int m = 0; m < 128; ++m) {
        const float w0 = W[m * 128 + lane];
        const float w1 = W[m * 128 + 64 + lane];
        #pragma unroll
        for (int rr = 0; rr < 4; ++rr) {
            const float av = rowlds[(wave * 4 + rr) * 128 + m];
            acc[rr][0] = fmaf(av, w0, acc[rr][0]);
            acc[rr][1] = fmaf(av, w1, acc[rr][1]);
        }
    }

    #pragma unroll
    for (int rr = 0; rr < 4; ++rr) {
        const int p = blk * 16 + wave * 4 + rr;
        float v0 = acc[rr][0], v1 = acc[rr][1];
        if (SSP) { v0 = sspf(v0); v1 = sspf(v1); }
        C[p * 128 + lane]      = v0;
        C[p * 128 + 64 + lane] = v1;
    }
}

// ---------------------------------------------------------------------------
// Row-centric MFMA pairs kernel over CSR-sorted pairs.
// Block b owns rows [b*16, b*16+16). All stages are MFMA; no atomics at all.
//   L1: act^T = ssp(Wf1^T x f^T + b1)                (f B-frags direct from global)
//   L2: Wij^T = Wf2^T x act^T + b2
//   X[p][c] = h[idx_j_p][c] * Wij[p][c] * rcut_p     (bf16, stored [c][p] in LDS)
//   AGG: aggT += X^T x S^T  (S = row-indicator, built in regs; D regs accumulate)
__global__ __launch_bounds__(256) void pairs_mfma_agg(
    const float* __restrict__ f_ij, const int* __restrict__ idx_i,
    const int* __restrict__ idx_j, const float* __restrict__ rcut,
    const float* __restrict__ Wf1, const float* __restrict__ bf1,
    const float* __restrict__ Wf2, const float* __restrict__ bf2,
    const float* __restrict__ h, const int* __restrict__ rowEnd,
    const int* __restrict__ perm, float* __restrict__ agg)
{
    // dual-use 16 KB buffer:
    //   act phase: [pair=64][c=128] bf16, row stride 256B, XOR swz ((p&7)<<4)
    //   X   phase: [c=128][pair=64] bf16, row stride 128B, XOR swz ((c&7)<<4)
    __shared__ unsigned short xt[64 * 128];
    __shared__ int   rrs[PB];
    __shared__ int   jjs[PB];
    __shared__ float rcs[PB];

    const int tid = threadIdx.x;
    const int w   = tid >> 6;       // wave 0..3: owns cols [w*32, w*32+32)
    const int l   = tid & 63;
    const int l15 = l & 15;
    const int l4  = l >> 4;
    const int swz = (l15 & 7) << 4;

    const int row0 = blockIdx.x * 16;
    const int s0 = (row0 == 0) ? 0 : rowEnd[row0 - 1];
    const int s1 = rowEnd[row0 + 15];

    // ---- weight fragments in registers ----
    short8v wf1a[2];
    #pragma unroll
    for (int kt2 = 0; kt2 < 2; ++kt2) {
        const int ck = w * 32 + kt2 * 16 + l15;
        #pragma unroll
        for (int e = 0; e < 8; ++e) {
            const int r = l4 * 8 + e;
            const float val = (r < RDIM) ? Wf1[r * 128 + ck] : 0.0f;
            wf1a[kt2][e] = (short)f2bf(val);
        }
    }
    short8v wf2a[2][4];
    #pragma unroll
    for (int mt = 0; mt < 2; ++mt) {
        const int c = w * 32 + mt * 16 + l15;
        #pragma unroll
        for (int ks = 0; ks < 4; ++ks) {
            #pragma unroll
            for (int e = 0; e < 8; ++e) {
                const int k = ks * 32 + l4 * 8 + e;
                wf2a[mt][ks][e] = (short)f2bf(Wf2[k * 128 + c]);
            }
        }
    }
    float b1v[2][4], b2v[2][4];
    #pragma unroll
    for (int t = 0; t < 2; ++t)
        #pragma unroll
        for (int j = 0; j < 4; ++j) {
            b1v[t][j] = bf1[w * 32 + t * 16 + l4 * 4 + j];
            b2v[t][j] = bf2[w * 32 + t * 16 + l4 * 4 + j];
        }

    // agg accumulator in MFMA D regs: accD[mt] holds aggT[c = w*32+mt*16+l4*4+j][r = l15]
    float4v accD[2];
    accD[0] = float4v{0.f, 0.f, 0.f, 0.f};
    accD[1] = float4v{0.f, 0.f, 0.f, 0.f};

    for (int s = s0; s < s1; s += PB) {
        __syncthreads();   // prev chunk's AGG reads of xt done; meta arrays free

        // ---- stage pair metadata (LDS) ----
        if (tid < PB) {
            const int q  = s + tid;
            const int qc = q < s1 ? q : s1 - 1;
            const int pid = perm[qc];
            rrs[tid] = idx_i[pid] - row0;            // in [0,16)
            jjs[tid] = idx_j[pid];
            rcs[tid] = (q < s1) ? rcut[pid] : 0.0f;  // pad slots contribute 0
        }

        // ---- layer-1 B-frags straight from global (k-contiguous per lane) ----
        short8v ffr[4];
        #pragma unroll
        for (int nt = 0; nt < 4; ++nt) {
            const int q = s + nt * 16 + l15;
            const int pid = perm[q < s1 ? q : s1 - 1];
            const float* fb = &f_ij[(size_t)pid * RDIM];
            float4 fa = {0.f, 0.f, 0.f, 0.f}, fc = {0.f, 0.f, 0.f, 0.f};
            if (l4 < 3) fa = *(const float4*)(fb + l4 * 8);       // l4=2 -> k 16..19
            if (l4 < 2) fc = *(const float4*)(fb + l4 * 8 + 4);
            ffr[nt][0] = (short)f2bf(fa.x); ffr[nt][1] = (short)f2bf(fa.y);
            ffr[nt][2] = (short)f2bf(fa.z); ffr[nt][3] = (short)f2bf(fa.w);
            ffr[nt][4] = (short)f2bf(fc.x); ffr[nt][5] = (short)f2bf(fc.y);
            ffr[nt][6] = (short)f2bf(fc.z); ffr[nt][7] = (short)f2bf(fc.w);
        }
        __syncthreads();   // metadata ready

        // ---- prefetch h rows (consumed after L2; latency hides under MFMA) ----
        float4 hv[4][2];
        #pragma unroll
        for (int nt = 0; nt < 4; ++nt) {
            const int gj = jjs[nt * 16 + l15] * 128;
            hv[nt][0] = *(const float4*)&h[gj + w * 32 + l4 * 4];
            hv[nt][1] = *(const float4*)&h[gj + w * 32 + 16 + l4 * 4];
        }

        // ---- layer 1: act^T = ssp(Wf1^T x f^T + b1) -> xt as [pair][c] ----
        #pragma unroll
        for (int kt2 = 0; kt2 < 2; ++kt2) {
            #pragma unroll
            for (int nt = 0; nt < 4; ++nt) {
                float4v acc1 = {0.f, 0.f, 0.f, 0.f};
                acc1 = __builtin_amdgcn_mfma_f32_16x16x32_bf16(wf1a[kt2], ffr[nt], acc1, 0, 0, 0);
                unsigned short pk[4];
                #pragma unroll
                for (int j = 0; j < 4; ++j)
                    pk[j] = f2bf(sspf_fast(acc1[j] + b1v[kt2][j]));
                const int row = nt * 16 + l15;
                const int byte = row * 256 + ((w * 64 + kt2 * 32 + l4 * 8) ^ swz);
                *(unsigned long long*)((char*)xt + byte) =
                    (unsigned long long)pk[0] | ((unsigned long long)pk[1] << 16) |
                    ((unsigned long long)pk[2] << 32) | ((unsigned long long)pk[3] << 48);
            }
        }
        __syncthreads();   // act ready

        // ---- layer 2: Wij^T = Wf2^T x act^T ----
        float4v a2[2][4];
        #pragma unroll
        for (int mt = 0; mt < 2; ++mt)
            #pragma unroll
            for (int nt = 0; nt < 4; ++nt)
                a2[mt][nt] = float4v{0.f, 0.f, 0.f, 0.f};

        #pragma unroll
        for (int ks = 0; ks < 4; ++ks) {
            short8v bfr[4];
            #pragma unroll
            for (int nt = 0; nt < 4; ++nt) {
                const int row = nt * 16 + l15;
                const int byte = row * 256 + ((ks * 64 + l4 * 16) ^ swz);
                bfr[nt] = *(const short8v*)((const char*)xt + byte);
            }
            #pragma unroll
            for (int mt = 0; mt < 2; ++mt)
                #pragma unroll
                for (int nt = 0; nt < 4; ++nt)
                    a2[mt][nt] = __builtin_amdgcn_mfma_f32_16x16x32_bf16(
                        wf2a[mt][ks], bfr[nt], a2[mt][nt], 0, 0, 0);
        }
        __syncthreads();   // act fully consumed; xt free for X

        // ---- X build: X[p][c] = h*(Wij+b2)*rcut -> bf16, stored [c][p] ----
        #pragma unroll
        for (int nt = 0; nt < 4; ++nt) {
            const int p = nt * 16 + l15;
            const float r = rcs[p];
            #pragma unroll
            for (int mt = 0; mt < 2; ++mt) {
                #pragma unroll
                for (int j = 0; j < 4; ++j) {
                    const int c = w * 32 + mt * 16 + l4 * 4 + j;
                    const float xv = hv[nt][mt][j] * ((a2[mt][nt][j] + b2v[mt][j]) * r);
                    const int byte = c * 128 + ((p * 2) ^ ((c & 7) << 4));
                    *(unsigned short*)((char*)xt + byte) = f2bf(xv);
                }
            }
        }
        __syncthreads();   // X ready

        // ---- AGG: aggT += X^T x S^T (S built in regs from rrs) ----
        #pragma unroll
        for (int ks = 0; ks < 2; ++ks) {
            short8v sfr;
            #pragma unroll
            for (int e = 0; e < 8; ++e) {
                const int pr = ks * 32 + l4 * 8 + e;
                sfr[e] = (rrs[pr] == l15) ? (short)0x3F80 : (short)0;  // bf16(1.0)
            }
            #pragma unroll
            for (int mt = 0; mt < 2; ++mt) {
                const int c = w * 32 + mt * 16 + l15;
                const int byte = c * 128 + ((ks * 64 + l4 * 16) ^ swz);
                const short8v xfr = *(const short8v*)((const char*)xt + byte);
                accD[mt] = __builtin_amdgcn_mfma_f32_16x16x32_bf16(xfr, sfr, accD[mt], 0, 0, 0);
            }
        }
    }

    // ---- write out: lane holds aggT[c = w*32+mt*16+l4*4+j][r = l15] ----
    #pragma unroll
    for (int mt = 0; mt < 2; ++mt) {
        float4 v;
        v.x = accD[mt][0]; v.y = accD[mt][1]; v.z = accD[mt][2]; v.w = accD[mt][3];
        *(float4*)&agg[(size_t)(row0 + l15) * 128 + w * 32 + mt * 16 + l4 * 4] = v;
    }
}

extern "C" void kernel_launch(void* const* d_in, const int* in_sizes, int n_in,
                              void* d_out, int out_size, void* d_ws, size_t ws_size,
                              hipStream_t stream) {
    const float* x     = (const float*)d_in[0];
    const float* f_ij  = (const float*)d_in[1];
    const int*   idx_i = (const int*)  d_in[2];
    const int*   idx_j = (const int*)  d_in[3];
    const float* rcut  = (const float*)d_in[4];
    const float* W_in  = (const float*)d_in[5];
    const float* b_in  = (const float*)d_in[6];
    const float* Wf1   = (const float*)d_in[7];
    const float* bf1   = (const float*)d_in[8];
    const float* Wf2   = (const float*)d_in[9];
    const float* bf2   = (const float*)d_in[10];
    const float* Wo1   = (const float*)d_in[11];
    const float* bo1   = (const float*)d_in[12];
    const float* Wo2   = (const float*)d_in[13];
    const float* bo2   = (const float*)d_in[14];
    float* out = (float*)d_out;

    const size_t SLAB = (size_t)BN * FDIM * sizeof(float);  // 4,096,000
    float* h   = (float*)d_ws;
    float* t1  = (float*)((char*)d_ws + SLAB);
    float* agg = (float*)((char*)d_ws + 2 * SLAB);
    // CSR scratch overlaid on t1 (t1 only live after pairs kernel)
    int* perm   = (int*)t1;                                   // 512000 ints
    int* cnt    = (int*)((char*)t1 + (size_t)NPAIR * 4);      // 8001 ints
    int* cursor = cnt + 8001;                                 // 8000 ints

    // CSR sort of pairs by idx_i
    hipMemsetAsync(cnt, 0, (BN + 1) * sizeof(int), stream);
    hist_kernel<<<NPAIR / 256, 256, 0, stream>>>(idx_i, cnt);
    scan_kernel<<<1, 1024, 0, stream>>>(cnt, cursor);
    scatter_kernel<<<NPAIR / 256, 256, 0, stream>>>(idx_i, cursor, perm);

    // h = x @ W_in + b_in
    rowgemm_kernel<false><<<BN / 16, 256, 0, stream>>>(x, W_in, b_in, h);

    // filter net (MFMA) + gather + MFMA segmented aggregation
    pairs_mfma_agg<<<BN / 16, 256, 0, stream>>>(
        f_ij, idx_i, idx_j, rcut, Wf1, bf1, Wf2, bf2, h, cursor, perm, agg);

    // out = ssp(agg @ Wo1 + bo1) @ Wo2 + bo2
    rowgemm_kernel<true><<<BN / 16, 256, 0, stream>>>(agg, Wo1, bo1, t1);
    rowgemm_kernel<false><<<BN / 16, 256, 0, stream>>>(t1, Wo2, bo2, out);
}